// Round 15
// baseline (239.287 us; speedup 1.0000x reference)
//
#include <hip/hip_runtime.h>
#include <hip/hip_bf16.h>

#define Bv 2
#define Tv 2048
#define Cv 1024
#define Hv 16
#define HSv 64
#define HIDv 2730
#define HIDP 2816
#define Mv 4096

using bf16x8 = __attribute__((ext_vector_type(8))) __bf16;
using f32x4  = __attribute__((ext_vector_type(4))) float;
typedef unsigned long long ull;

__device__ __forceinline__ void gload_lds16(const void* g, void* l) {
    auto gp = (const __attribute__((address_space(1))) unsigned int*)(unsigned long long)(uintptr_t)g;
    auto lp = (__attribute__((address_space(3))) unsigned int*)(unsigned int)(uintptr_t)l;
    __builtin_amdgcn_global_load_lds(gp, lp, 16, 0, 0);
}

// ---------------- fused weight cast ----------------
struct CastSeg { const float* s; __bf16* d; long nsrc; long ntot; int sc; int dc; };
struct CastArgs { CastSeg seg[7]; };

__global__ __launch_bounds__(256) void k_castall(CastArgs a) {
    long gid = (long)blockIdx.x * 256 + threadIdx.x;
    long gstr = (long)gridDim.x * 256;
#pragma unroll 1
    for (int g = 0; g < 7; ++g) {
        CastSeg sg = a.seg[g];
        if (sg.sc == 0) {
            long n4 = sg.ntot >> 2;
            for (long i = gid; i < n4; i += gstr) {
                long base = i * 4;
                float4 v = {0.f, 0.f, 0.f, 0.f};
                if (base < sg.nsrc) v = *(const float4*)(sg.s + base);
                __bf16 o[4] = {(__bf16)v.x, (__bf16)v.y, (__bf16)v.z, (__bf16)v.w};
                *(ull*)(sg.d + base) = *(ull*)o;
            }
        } else {
            long n8 = sg.ntot >> 3;
            for (long i8 = gid; i8 < n8; i8 += gstr) {
                long base = i8 * 8;
                int r = (int)(base / sg.dc), c = (int)(base % sg.dc);
                __bf16 o[8];
                const float* srow = sg.s + (long)r * sg.sc + c;
                if (c + 8 <= sg.sc) {
#pragma unroll
                    for (int q = 0; q < 4; ++q) {
                        float2 v = *(const float2*)(srow + q * 2);
                        o[q * 2] = (__bf16)v.x; o[q * 2 + 1] = (__bf16)v.y;
                    }
                } else {
#pragma unroll
                    for (int e = 0; e < 8; ++e)
                        o[e] = (c + e < sg.sc) ? (__bf16)srow[e] : (__bf16)0.0f;
                }
                *(bf16x8*)(sg.d + base) = *(bf16x8*)o;
            }
        }
    }
}

// ---------------- rmsnorm (IN=0: f32 input, IN=1: bf16 input) -> bf16 out only ----------------
template <int IN>
__global__ __launch_bounds__(256) void k_rmsnorm(const void* __restrict__ xin,
                                                 const float* __restrict__ w,
                                                 __bf16* __restrict__ yh) {
    int row = blockIdx.x, t = threadIdx.x;
    float v[4];
    if (IN == 0) {
        float4 a = ((const float4*)((const float*)xin + (size_t)row * Cv))[t];
        v[0] = a.x; v[1] = a.y; v[2] = a.z; v[3] = a.w;
    } else {
        ull u = ((const ull*)((const __bf16*)xin + (size_t)row * Cv))[t];
        const __bf16* bp = (const __bf16*)&u;
#pragma unroll
        for (int e = 0; e < 4; ++e) v[e] = (float)bp[e];
    }
    float ss = v[0] * v[0] + v[1] * v[1] + v[2] * v[2] + v[3] * v[3];
#pragma unroll
    for (int m = 1; m < 64; m <<= 1) ss += __shfl_xor(ss, m);
    __shared__ float red[4];
    if ((t & 63) == 0) red[t >> 6] = ss;
    __syncthreads();
    float tot = red[0] + red[1] + red[2] + red[3];
    float sc = rsqrtf(tot * (1.0f / Cv) + 1e-6f);
    float4 wv = ((const float4*)w)[t];
    __bf16 o[4];
    o[0] = (__bf16)(v[0] * sc * wv.x); o[1] = (__bf16)(v[1] * sc * wv.y);
    o[2] = (__bf16)(v[2] * sc * wv.z); o[3] = (__bf16)(v[3] * sc * wv.w);
    *(ull*)(yh + (size_t)row * Cv + t * 4) = *(ull*)o;
}

// ---------------- GEMM (m97 + T2 swizzle + XCD-chunk, single-buffer) ----------------
// EPI 1: outF = acc + bias + (f32)residH ; EPI 2: outH = bf16(same)
// EPI 4: fused RoPE epilogue -> qOut (rope'd + SCL-prescaled Q), kOut (KR), vOut (VT)
template <int BM, int EPI>
__global__ __launch_bounds__(256) void k_gemm(
    const __bf16* __restrict__ A, const __bf16* __restrict__ Bm,
    int M, int N, int K,
    float* __restrict__ outF, __bf16* __restrict__ outH,
    const float* __restrict__ bias,
    const __bf16* __restrict__ residH,
    __bf16* __restrict__ qOut, __bf16* __restrict__ kOut, __bf16* __restrict__ vOut,
    const float* __restrict__ cosT, const float* __restrict__ sinT) {
    constexpr int NN = (BM == 128) ? 4 : 2;
    __shared__ __align__(16) __bf16 As[BM][64];
    __shared__ __align__(16) __bf16 Bs[128][64];
    int tid = threadIdx.x, lane = tid & 63, wave = tid >> 6;
    int nm = M / BM;
    int nwg = nm * (N >> 7);
    int flat = blockIdx.x;
    int orig = (flat & 7) * (nwg >> 3) + (flat >> 3);
    int m0 = (orig % nm) * BM;
    int n0 = (orig / nm) * 128;
    int wro = (BM == 128) ? (wave >> 1) * 64 : 0;
    int wco = (BM == 128) ? (wave & 1) * 64 : wave * 32;
    int fr = lane & 15, fo2 = (lane >> 4) * 16;
    int lr = lane >> 3, lc = (lane & 7) * 8;
    f32x4 acc[4][NN] = {};
    for (int k0 = 0; k0 < K; k0 += 64) {
        __syncthreads();
        int arow0 = wave * (BM / 4);
#pragma unroll
        for (int i = 0; i < BM / 32; ++i) {
            int r = arow0 + i * 8 + lr;
            gload_lds16(A + (long)(m0 + r) * K + k0 + (lc ^ ((r & 7) << 3)), &As[r][lc]);
        }
        int brow0 = wave * 32;
#pragma unroll
        for (int i = 0; i < 4; ++i) {
            int r = brow0 + i * 8 + lr;
            gload_lds16(Bm + (long)(n0 + r) * K + k0 + (lc ^ ((r & 7) << 3)), &Bs[r][lc]);
        }
        __syncthreads();
#pragma unroll
        for (int s = 0; s < 2; ++s) {
            bf16x8 af[4], bf[NN];
#pragma unroll
            for (int m = 0; m < 4; ++m) {
                int r = wro + m * 16 + fr;
                af[m] = *(const bf16x8*)((const char*)&As[r][0] + ((s * 64 + fo2) ^ ((r & 7) << 4)));
            }
#pragma unroll
            for (int n = 0; n < NN; ++n) {
                int r = wco + n * 16 + fr;
                bf[n] = *(const bf16x8*)((const char*)&Bs[r][0] + ((s * 64 + fo2) ^ ((r & 7) << 4)));
            }
            __builtin_amdgcn_s_setprio(1);
#pragma unroll
            for (int m = 0; m < 4; ++m)
#pragma unroll
                for (int n = 0; n < NN; ++n)
                    acc[m][n] = __builtin_amdgcn_mfma_f32_16x16x32_bf16(af[m], bf[n], acc[m][n], 0, 0, 0);
            __builtin_amdgcn_s_setprio(0);
        }
    }
    int fq = (lane >> 4) * 4;
    if (EPI == 1 || EPI == 2) {
#pragma unroll
        for (int m = 0; m < 4; ++m)
#pragma unroll
            for (int n = 0; n < NN; ++n) {
                int row = m0 + wro + m * 16 + fq;
                int col = n0 + wco + n * 16 + fr;
#pragma unroll
                for (int r = 0; r < 4; ++r) {
                    long idx = (long)(row + r) * N + col;
                    float v = acc[m][n][r] + bias[col] + (float)residH[idx];
                    if (EPI == 1) outF[idx] = v;
                    else          outH[idx] = (__bf16)v;
                }
            }
    } else {
        const float SCL = 0.125f * 1.44269504f;
#pragma unroll
        for (int n = 0; n < NN; ++n) {
            int col = n0 + wco + n * 16 + fr;
            int part = col >> 10;
            int cn = col & 1023;
            int hh = cn >> 6, d = cn & 63, ii = d >> 1;
            bool evn = (d & 1) == 0;
#pragma unroll
            for (int m = 0; m < 4; ++m) {
                int row = m0 + wro + m * 16 + fq;
                int bh = (row >> 11) * 16 + hh;
                int tb = row & (Tv - 1);
                if (part == 2) {
                    int X = (d & 7) << 3;
                    int tile0 = tb & ~63, toff = tb & 63;
                    __bf16 ov[4];
#pragma unroll
                    for (int r = 0; r < 4; ++r) ov[r] = (__bf16)acc[m][n][r];
                    *(ull*)(vOut + ((long)bh * 64 + d) * Tv + tile0 + (toff ^ X)) = *(ull*)ov;
                } else {
                    float pxv[4];
#pragma unroll
                    for (int r = 0; r < 4; ++r) pxv[r] = __shfl_xor(acc[m][n][r], 1);
                    if (evn) {
#pragma unroll
                        for (int r = 0; r < 4; ++r) {
                            int t = tb + r;
                            float c = cosT[t * 32 + ii], s = sinT[t * 32 + ii];
                            float x0 = acc[m][n][r], x1 = pxv[r];
                            float r0 = x0 * c - x1 * s;
                            float r1 = x0 * s + x1 * c;
                            if (part == 0) {
                                __bf16 pr[2] = {(__bf16)(r0 * SCL), (__bf16)(r1 * SCL)};
                                *(unsigned int*)(qOut + (long)(row + r) * 1024 + cn) = *(unsigned int*)pr;
                            } else {
                                __bf16 pr[2] = {(__bf16)r0, (__bf16)r1};
                                char* base = (char*)(kOut + ((long)bh * Tv + t) * 64);
                                *(unsigned int*)(base + ((4 * ii) ^ ((t & 7) << 4))) = *(unsigned int*)pr;
                            }
                        }
                    }
                }
            }
        }
    }
}

// ---------------- fused FFN1+FFN2: 128x64 dual-acc, 1408 blocks (occupancy-first) ----------------
__global__ __launch_bounds__(256, 4) void k_ffn(const __bf16* __restrict__ A,
                                                const __bf16* __restrict__ B1,
                                                const __bf16* __restrict__ B2,
                                                const float* __restrict__ b1,
                                                const float* __restrict__ b2,
                                                __bf16* __restrict__ outH) {
    __shared__ __align__(16) __bf16 As[128][64];    // 16 KB
    __shared__ __align__(16) __bf16 B1s[64][64];    // 8 KB
    __shared__ __align__(16) __bf16 B2s[64][64];    // 8 KB
    int tid = threadIdx.x, lane = tid & 63, wave = tid >> 6;
    int nwg = 32 * (HIDP >> 6);                     // 32 * 44 = 1408
    int flat = blockIdx.x;
    int orig = (flat & 7) * (nwg >> 3) + (flat >> 3);
    int m0 = (orig & 31) * 128;                     // m-fast (nm = 32)
    int n0 = (orig >> 5) * 64;
    int wro = (wave >> 1) * 64, wco = (wave & 1) * 32;
    int fr = lane & 15, fo2 = (lane >> 4) * 16;
    int sr = tid >> 3, sc = (tid & 7) * 8;
    f32x4 acc1[4][2] = {}, acc2[4][2] = {};
    for (int k0 = 0; k0 < Cv; k0 += 64) {
        __syncthreads();
#pragma unroll
        for (int i = 0; i < 4; ++i) {
            int r = i * 32 + sr;
            gload_lds16(A + (long)(m0 + r) * Cv + k0 + (sc ^ ((r & 7) << 3)), &As[r][sc]);
        }
#pragma unroll
        for (int i = 0; i < 2; ++i) {
            int r = i * 32 + sr;
            int scs = sc ^ ((r & 7) << 3);
            gload_lds16(B1 + (long)(n0 + r) * Cv + k0 + scs, &B1s[r][sc]);
            gload_lds16(B2 + (long)(n0 + r) * Cv + k0 + scs, &B2s[r][sc]);
        }
        __syncthreads();
#pragma unroll
        for (int s = 0; s < 2; ++s) {
            bf16x8 af[4], b1f[2], b2f[2];
#pragma unroll
            for (int m = 0; m < 4; ++m) {
                int r = wro + m * 16 + fr;
                af[m] = *(const bf16x8*)((const char*)&As[r][0] + ((s * 64 + fo2) ^ ((r & 7) << 4)));
            }
#pragma unroll
            for (int n = 0; n < 2; ++n) {
                int r = wco + n * 16 + fr;
                b1f[n] = *(const bf16x8*)((const char*)&B1s[r][0] + ((s * 64 + fo2) ^ ((r & 7) << 4)));
                b2f[n] = *(const bf16x8*)((const char*)&B2s[r][0] + ((s * 64 + fo2) ^ ((r & 7) << 4)));
            }
            __builtin_amdgcn_s_setprio(1);
#pragma unroll
            for (int m = 0; m < 4; ++m)
#pragma unroll
                for (int n = 0; n < 2; ++n) {
                    acc1[m][n] = __builtin_amdgcn_mfma_f32_16x16x32_bf16(af[m], b1f[n], acc1[m][n], 0, 0, 0);
                    acc2[m][n] = __builtin_amdgcn_mfma_f32_16x16x32_bf16(af[m], b2f[n], acc2[m][n], 0, 0, 0);
                }
            __builtin_amdgcn_s_setprio(0);
        }
    }
    int fq = (lane >> 4) * 4;
#pragma unroll
    for (int m = 0; m < 4; ++m)
#pragma unroll
        for (int n = 0; n < 2; ++n) {
            int row = m0 + wro + m * 16 + fq;
            int col = n0 + wco + n * 16 + fr;
            float b1v = (col < HIDv) ? b1[col] : 0.0f;
            float b2v = (col < HIDv) ? b2[col] : 0.0f;
#pragma unroll
            for (int r = 0; r < 4; ++r) {
                float c1 = acc1[m][n][r] + b1v;
                float c2 = acc2[m][n][r] + b2v;
                float sw = c1 * (1.0f + __expf(-c1));
                outH[(long)(row + r) * HIDP + col] = (__bf16)(sw * c2);
            }
        }
}

// ---------------- flash attention (r13: QBLK=64, KBLK=128, single-buffer, 4 blk/CU) ----------------
__global__ __launch_bounds__(256) void k_attn(const __bf16* __restrict__ Q,
                                              const __bf16* __restrict__ KR,
                                              const __bf16* __restrict__ VT,
                                              __bf16* __restrict__ O) {
    __shared__ __align__(16) __bf16 Ks[128][64];
    __shared__ __align__(16) __bf16 Vs[64][128];
    __shared__ __align__(16) __bf16 Ps[4][16][64];
    int tid = threadIdx.x, lane = tid & 63, w = tid >> 6;
    int bh = blockIdx.x & 31;
    int qt = 31 - (blockIdx.x >> 5);
    int q0 = qt * 64;
    int hi = qt & 1;
    int b = bh >> 4, h = bh & 15;
    const long qbase = ((long)b * Tv) * Cv + h * HSv;
    const long kbase = (long)bh * Tv * 64;
    const long vbase = (long)bh * 64 * Tv;
    int fr = lane & 15, g = lane >> 4;
    int go = g * 8;
    int xr = (fr & 7) << 4;
    int qrow = q0 + w * 16 + fr;
    bf16x8 qf0 = *(const bf16x8*)(Q + qbase + (long)qrow * Cv + go);
    bf16x8 qf1 = *(const bf16x8*)(Q + qbase + (long)qrow * Cv + 32 + go);

    bf16x8 ones;
#pragma unroll
    for (int e = 0; e < 8; ++e) ones[e] = (__bf16)1.0f;

    f32x4 o[4] = {};
    f32x4 ls = {};
    float mrow = -INFINITY;

    auto stage = [&](int j0) {
#pragma unroll
        for (int i = 0; i < 4; ++i) {
            int rk = i * 32 + w * 8 + (lane >> 3);
            gload_lds16(KR + kbase + (long)(j0 + rk) * 64 + (lane & 7) * 8,
                        &Ks[rk][(lane & 7) * 8]);
        }
#pragma unroll
        for (int i = 0; i < 4; ++i) {
            int rv = w * 16 + i * 4 + (lane >> 4);
            gload_lds16(VT + vbase + (long)rv * Tv + j0 + (lane & 15) * 8,
                        &Vs[rv][(lane & 15) * 8]);
        }
    };

    int nt = (qt >> 1) + 1;
    stage(0);
    for (int t = 0; t < nt; ++t) {
        __syncthreads();
        bool diag = (t == nt - 1);
        int kkmax = diag ? (w + (hi ? 4 : 0)) : 7;
        f32x4 s4[8];
        __builtin_amdgcn_s_setprio(1);
#pragma unroll
        for (int kk = 0; kk < 8; ++kk) {
            if (kk <= kkmax) {
                int key = kk * 16 + fr;
                const char* krow = (const char*)&Ks[key][0];
                bf16x8 kf0 = *(const bf16x8*)(krow + ((go * 2) ^ ((key & 7) << 4)));
                bf16x8 kf1 = *(const bf16x8*)(krow + ((64 + go * 2) ^ ((key & 7) << 4)));
                f32x4 z = {};
                z = __builtin_amdgcn_mfma_f32_16x16x32_bf16(kf0, qf0, z, 0, 0, 0);
                z = __builtin_amdgcn_mfma_f32_16x16x32_bf16(kf1, qf1, z, 0, 0, 0);
                s4[kk] = z;
            } else {
                f32x4 ninf = {-INFINITY, -INFINITY, -INFINITY, -INFINITY};
                s4[kk] = ninf;
            }
        }
        __builtin_amdgcn_s_setprio(0);
        if (diag) {
            int qloc = hi * 64 + w * 16 + fr;
#pragma unroll
            for (int kk = 0; kk < 8; ++kk)
#pragma unroll
                for (int r = 0; r < 4; ++r) {
                    int key = kk * 16 + g * 4 + r;
                    if (key > qloc) s4[kk][r] = -INFINITY;
                }
        }
        float pmax = s4[0][0];
#pragma unroll
        for (int kk = 0; kk < 8; ++kk)
#pragma unroll
            for (int r = 0; r < 4; ++r) pmax = fmaxf(pmax, s4[kk][r]);
        pmax = fmaxf(pmax, __shfl_xor(pmax, 16));
        pmax = fmaxf(pmax, __shfl_xor(pmax, 32));
        if (!__all(pmax - mrow <= 8.0f)) {
            float mn = fmaxf(mrow, pmax);
            float alpha = exp2f(mrow - mn);
            mrow = mn;
#pragma unroll
            for (int r = 0; r < 4; ++r) ls[r] *= alpha;
#pragma unroll
            for (int fb = 0; fb < 4; ++fb)
#pragma unroll
                for (int r = 0; r < 4; ++r) o[fb][r] *= alpha;
        }
        char* prow = (char*)&Ps[w][fr][0];
#pragma unroll
        for (int hf = 0; hf < 2; ++hf) {
            if (diag && !hi && hf == 1) break;
#pragma unroll
            for (int kk = 0; kk < 4; ++kk) {
                int ks = hf * 4 + kk;
                __bf16 pk[4];
#pragma unroll
                for (int r = 0; r < 4; ++r) pk[r] = (__bf16)exp2f(s4[ks][r] - mrow);
                *(ull*)(prow + ((kk * 32 + g * 8) ^ xr)) = *(ull*)pk;
            }
            bf16x8 pa0 = *(const bf16x8*)(prow + ((g * 16) ^ xr));
            bf16x8 pa1 = *(const bf16x8*)(prow + ((64 + g * 16) ^ xr));
            __builtin_amdgcn_s_setprio(1);
            ls = __builtin_amdgcn_mfma_f32_16x16x32_bf16(ones, pa0, ls, 0, 0, 0);
            ls = __builtin_amdgcn_mfma_f32_16x16x32_bf16(ones, pa1, ls, 0, 0, 0);
#pragma unroll
            for (int fb = 0; fb < 4; ++fb) {
                int vrow = fb * 16 + fr;
                const char* vrd = (const char*)&Vs[vrow][0];
                bf16x8 v0 = *(const bf16x8*)(vrd + hf * 128 + ((go * 2) ^ ((vrow & 7) << 4)));
                bf16x8 v1 = *(const bf16x8*)(vrd + hf * 128 + ((64 + go * 2) ^ ((vrow & 7) << 4)));
                o[fb] = __builtin_amdgcn_mfma_f32_16x16x32_bf16(v0, pa0, o[fb], 0, 0, 0);
                o[fb] = __builtin_amdgcn_mfma_f32_16x16x32_bf16(v1, pa1, o[fb], 0, 0, 0);
            }
            __builtin_amdgcn_s_setprio(0);
        }
        if (t + 1 < nt) {
            __syncthreads();
            stage((t + 1) * 128);
        }
    }
    float rl = 1.0f / ls[0];
#pragma unroll
    for (int fb = 0; fb < 4; ++fb) {
        __bf16 ov[4];
#pragma unroll
        for (int r = 0; r < 4; ++r) ov[r] = (__bf16)(o[fb][r] * rl);
        *(ull*)(O + qbase + (long)qrow * Cv + fb * 16 + g * 4) = *(ull*)ov;
    }
}

// ---------------- launch ----------------
extern "C" void kernel_launch(void* const* d_in, const int* in_sizes, int n_in,
                              void* d_out, int out_size, void* d_ws, size_t ws_size,
                              hipStream_t stream) {
    const float* x    = (const float*)d_in[0];
    const float* ln1w = (const float*)d_in[1];
    const float* Wq   = (const float*)d_in[2];
    const float* Wk   = (const float*)d_in[3];
    const float* Wv   = (const float*)d_in[4];
    const float* Wo   = (const float*)d_in[5];
    const float* bo   = (const float*)d_in[6];
    const float* w1   = (const float*)d_in[7];
    const float* b1   = (const float*)d_in[8];
    const float* w2   = (const float*)d_in[9];
    const float* b2   = (const float*)d_in[10];
    const float* w3   = (const float*)d_in[11];
    const float* b3   = (const float*)d_in[12];
    const float* ln2w = (const float*)d_in[13];
    const float* cosT = (const float*)d_in[14];
    const float* sinT = (const float*)d_in[15];
    float* out = (float*)d_out;

    char* p = (char*)d_ws;
    auto alloc = [&](size_t bytes) {
        char* r = p;
        p += (bytes + 255) & ~(size_t)255;
        return r;
    };
    __bf16* qh  = (__bf16*)alloc((size_t)Mv * Cv * 2);
    __bf16* ah  = (__bf16*)alloc((size_t)Mv * Cv * 2);
    __bf16* x1h = (__bf16*)alloc((size_t)Mv * Cv * 2);
    __bf16* x2h = (__bf16*)alloc((size_t)Mv * Cv * 2);
    __bf16* x3h = (__bf16*)alloc((size_t)Mv * Cv * 2);
    __bf16* KR  = (__bf16*)alloc((size_t)Bv * Hv * Tv * HSv * 2);
    __bf16* VT  = (__bf16*)alloc((size_t)Bv * Hv * HSv * Tv * 2);
    __bf16* hh  = (__bf16*)alloc((size_t)Mv * HIDP * 2);
    __bf16* wqkvh = (__bf16*)alloc((size_t)3072 * Cv * 2);
    __bf16* woh = (__bf16*)alloc((size_t)Cv * Cv * 2);
    __bf16* w1h = (__bf16*)alloc((size_t)HIDP * Cv * 2);
    __bf16* w2h = (__bf16*)alloc((size_t)HIDP * Cv * 2);
    __bf16* w3h = (__bf16*)alloc((size_t)Cv * HIDP * 2);

    const long nCC = (long)Cv * Cv;
    CastArgs ca;
    ca.seg[0] = {Wq, wqkvh,           nCC, nCC, 0, 0};
    ca.seg[1] = {Wk, wqkvh + nCC,     nCC, nCC, 0, 0};
    ca.seg[2] = {Wv, wqkvh + 2 * nCC, nCC, nCC, 0, 0};
    ca.seg[3] = {Wo, woh,             nCC, nCC, 0, 0};
    ca.seg[4] = {w1, w1h, (long)HIDv * Cv, (long)HIDP * Cv, 0, 0};
    ca.seg[5] = {w2, w2h, (long)HIDv * Cv, (long)HIDP * Cv, 0, 0};
    ca.seg[6] = {w3, w3h, (long)Cv * HIDv, (long)Cv * HIDP, HIDv, HIDP};
    k_castall<<<2048, 256, 0, stream>>>(ca);

    k_rmsnorm<0><<<Mv, 256, 0, stream>>>(x, ln1w, x1h);

    // QKV GEMM with fused RoPE(+Q prescale) + V-transpose epilogue
    k_gemm<128, 4><<<768, 256, 0, stream>>>(x1h, wqkvh, Mv, 3072, Cv,
        nullptr, nullptr, nullptr, nullptr, qh, KR, VT, cosT, sinT);

    k_attn<<<1024, 256, 0, stream>>>(qh, KR, VT, ah);

    // x2 = bf16(x1 + attn @ Wo^T + bo)
    k_gemm<64, 2><<<512, 256, 0, stream>>>(ah, woh, Mv, Cv, Cv,
        nullptr, x2h, bo, x1h, nullptr, nullptr, nullptr, nullptr, nullptr);

    k_rmsnorm<1><<<Mv, 256, 0, stream>>>(x2h, ln2w, x3h);

    // hh = swish_bug(x3@w1^T + b1) * (x3@w2^T + b2)  — 128x64 dual, 1408 blocks
    k_ffn<<<1408, 256, 0, stream>>>(x3h, w1h, w2h, b1, b2, hh);

    // out = x3 + hh @ w3^T + b3  (f32 out, bf16 resid)
    k_gemm<64, 1><<<512, 256, 0, stream>>>(hh, w3h, Mv, Cv, HIDP,
        out, nullptr, b3, x3h, nullptr, nullptr, nullptr, nullptr, nullptr);
}

// Round 16
// 225.791 us; speedup vs baseline: 1.0598x; 1.0598x over previous
//
#include <hip/hip_runtime.h>
#include <hip/hip_bf16.h>

#define Bv 2
#define Tv 2048
#define Cv 1024
#define Hv 16
#define HSv 64
#define HIDv 2730
#define HIDP 2816
#define Mv 4096

using bf16x8 = __attribute__((ext_vector_type(8))) __bf16;
using f32x4  = __attribute__((ext_vector_type(4))) float;
typedef unsigned long long ull;

__device__ __forceinline__ void gload_lds16(const void* g, void* l) {
    auto gp = (const __attribute__((address_space(1))) unsigned int*)(unsigned long long)(uintptr_t)g;
    auto lp = (__attribute__((address_space(3))) unsigned int*)(unsigned int)(uintptr_t)l;
    __builtin_amdgcn_global_load_lds(gp, lp, 16, 0, 0);
}

// ---------------- fused weight cast + rmsnorm1 (independent work, one launch) ----------------
struct CastSeg { const float* s; __bf16* d; long nsrc; long ntot; int sc; int dc; };
struct CastArgs { CastSeg seg[7]; };

__global__ __launch_bounds__(256) void k_prep(CastArgs a,
                                              const float* __restrict__ x,
                                              const float* __restrict__ ln1w,
                                              __bf16* __restrict__ x1h) {
    if (blockIdx.x >= 2048) {
        // rmsnorm1: f32 x -> bf16 x1h
        int row = blockIdx.x - 2048, t = threadIdx.x;
        float4 av = ((const float4*)(x + (size_t)row * Cv))[t];
        float v[4] = {av.x, av.y, av.z, av.w};
        float ss = v[0] * v[0] + v[1] * v[1] + v[2] * v[2] + v[3] * v[3];
#pragma unroll
        for (int m = 1; m < 64; m <<= 1) ss += __shfl_xor(ss, m);
        __shared__ float red[4];
        if ((t & 63) == 0) red[t >> 6] = ss;
        __syncthreads();
        float tot = red[0] + red[1] + red[2] + red[3];
        float sc = rsqrtf(tot * (1.0f / Cv) + 1e-6f);
        float4 wv = ((const float4*)ln1w)[t];
        __bf16 o[4];
        o[0] = (__bf16)(v[0] * sc * wv.x); o[1] = (__bf16)(v[1] * sc * wv.y);
        o[2] = (__bf16)(v[2] * sc * wv.z); o[3] = (__bf16)(v[3] * sc * wv.w);
        *(ull*)(x1h + (size_t)row * Cv + t * 4) = *(ull*)o;
        return;
    }
    long gid = (long)blockIdx.x * 256 + threadIdx.x;
    long gstr = 2048L * 256;
#pragma unroll 1
    for (int g = 0; g < 7; ++g) {
        CastSeg sg = a.seg[g];
        if (sg.sc == 0) {
            long n4 = sg.ntot >> 2;
            for (long i = gid; i < n4; i += gstr) {
                long base = i * 4;
                float4 v = {0.f, 0.f, 0.f, 0.f};
                if (base < sg.nsrc) v = *(const float4*)(sg.s + base);
                __bf16 o[4] = {(__bf16)v.x, (__bf16)v.y, (__bf16)v.z, (__bf16)v.w};
                *(ull*)(sg.d + base) = *(ull*)o;
            }
        } else {
            long n8 = sg.ntot >> 3;
            for (long i8 = gid; i8 < n8; i8 += gstr) {
                long base = i8 * 8;
                int r = (int)(base / sg.dc), c = (int)(base % sg.dc);
                __bf16 o[8];
                const float* srow = sg.s + (long)r * sg.sc + c;
                if (c + 8 <= sg.sc) {
#pragma unroll
                    for (int q = 0; q < 4; ++q) {
                        float2 v = *(const float2*)(srow + q * 2);
                        o[q * 2] = (__bf16)v.x; o[q * 2 + 1] = (__bf16)v.y;
                    }
                } else {
#pragma unroll
                    for (int e = 0; e < 8; ++e)
                        o[e] = (c + e < sg.sc) ? (__bf16)srow[e] : (__bf16)0.0f;
                }
                *(bf16x8*)(sg.d + base) = *(bf16x8*)o;
            }
        }
    }
}

// ---------------- rmsnorm (bf16 input) -> bf16 out ----------------
__global__ __launch_bounds__(256) void k_rmsnorm_h(const __bf16* __restrict__ xin,
                                                   const float* __restrict__ w,
                                                   __bf16* __restrict__ yh) {
    int row = blockIdx.x, t = threadIdx.x;
    ull u = ((const ull*)(xin + (size_t)row * Cv))[t];
    const __bf16* bp = (const __bf16*)&u;
    float v[4];
#pragma unroll
    for (int e = 0; e < 4; ++e) v[e] = (float)bp[e];
    float ss = v[0] * v[0] + v[1] * v[1] + v[2] * v[2] + v[3] * v[3];
#pragma unroll
    for (int m = 1; m < 64; m <<= 1) ss += __shfl_xor(ss, m);
    __shared__ float red[4];
    if ((t & 63) == 0) red[t >> 6] = ss;
    __syncthreads();
    float tot = red[0] + red[1] + red[2] + red[3];
    float sc = rsqrtf(tot * (1.0f / Cv) + 1e-6f);
    float4 wv = ((const float4*)w)[t];
    __bf16 o[4];
    o[0] = (__bf16)(v[0] * sc * wv.x); o[1] = (__bf16)(v[1] * sc * wv.y);
    o[2] = (__bf16)(v[2] * sc * wv.z); o[3] = (__bf16)(v[3] * sc * wv.w);
    *(ull*)(yh + (size_t)row * Cv + t * 4) = *(ull*)o;
}

// ---------------- GEMM (m97 + T2 swizzle + XCD-chunk, single-buffer, generic tile) ----------------
// EPI 1: outF = acc + bias + (f32)residH ; EPI 2: outH = bf16(same)
// EPI 4: fused RoPE epilogue -> qOut (rope'd + SCL-prescaled Q), kOut (KR), vOut (VT)
template <int BM, int BN, int EPI>
__global__ __launch_bounds__(256, (BM == 64) ? 4 : 1) void k_gemm(
    const __bf16* __restrict__ A, const __bf16* __restrict__ Bm,
    int M, int N, int K,
    float* __restrict__ outF, __bf16* __restrict__ outH,
    const float* __restrict__ bias,
    const __bf16* __restrict__ residH,
    __bf16* __restrict__ qOut, __bf16* __restrict__ kOut, __bf16* __restrict__ vOut,
    const float* __restrict__ cosT, const float* __restrict__ sinT) {
    constexpr int MM = BM / 32, NN = BN / 32;
    __shared__ __align__(16) __bf16 As[BM][64];
    __shared__ __align__(16) __bf16 Bs[BN][64];
    int tid = threadIdx.x, lane = tid & 63, wave = tid >> 6;
    int nm = M / BM;
    int nwg = nm * (N / BN);
    int flat = blockIdx.x;
    int orig = (flat & 7) * (nwg >> 3) + (flat >> 3);
    int m0 = (orig % nm) * BM;
    int n0 = (orig / nm) * BN;
    int wro = (wave >> 1) * (BM / 2);
    int wco = (wave & 1) * (BN / 2);
    int fr = lane & 15, fo2 = (lane >> 4) * 16;
    int lr = lane >> 3, lc = (lane & 7) * 8;
    f32x4 acc[MM][NN] = {};
    for (int k0 = 0; k0 < K; k0 += 64) {
        __syncthreads();
        int arow0 = wave * (BM / 4);
#pragma unroll
        for (int i = 0; i < BM / 32; ++i) {
            int r = arow0 + i * 8 + lr;
            gload_lds16(A + (long)(m0 + r) * K + k0 + (lc ^ ((r & 7) << 3)), &As[r][lc]);
        }
        int brow0 = wave * (BN / 4);
#pragma unroll
        for (int i = 0; i < BN / 32; ++i) {
            int r = brow0 + i * 8 + lr;
            gload_lds16(Bm + (long)(n0 + r) * K + k0 + (lc ^ ((r & 7) << 3)), &Bs[r][lc]);
        }
        __syncthreads();
#pragma unroll
        for (int s = 0; s < 2; ++s) {
            bf16x8 af[MM], bf[NN];
#pragma unroll
            for (int m = 0; m < MM; ++m) {
                int r = wro + m * 16 + fr;
                af[m] = *(const bf16x8*)((const char*)&As[r][0] + ((s * 64 + fo2) ^ ((r & 7) << 4)));
            }
#pragma unroll
            for (int n = 0; n < NN; ++n) {
                int r = wco + n * 16 + fr;
                bf[n] = *(const bf16x8*)((const char*)&Bs[r][0] + ((s * 64 + fo2) ^ ((r & 7) << 4)));
            }
            __builtin_amdgcn_s_setprio(1);
#pragma unroll
            for (int m = 0; m < MM; ++m)
#pragma unroll
                for (int n = 0; n < NN; ++n)
                    acc[m][n] = __builtin_amdgcn_mfma_f32_16x16x32_bf16(af[m], bf[n], acc[m][n], 0, 0, 0);
            __builtin_amdgcn_s_setprio(0);
        }
    }
    int fq = (lane >> 4) * 4;
    if (EPI == 1 || EPI == 2) {
#pragma unroll
        for (int m = 0; m < MM; ++m)
#pragma unroll
            for (int n = 0; n < NN; ++n) {
                int row = m0 + wro + m * 16 + fq;
                int col = n0 + wco + n * 16 + fr;
#pragma unroll
                for (int r = 0; r < 4; ++r) {
                    long idx = (long)(row + r) * N + col;
                    float v = acc[m][n][r] + bias[col] + (float)residH[idx];
                    if (EPI == 1) outF[idx] = v;
                    else          outH[idx] = (__bf16)v;
                }
            }
    } else {
        const float SCL = 0.125f * 1.44269504f;
#pragma unroll
        for (int n = 0; n < NN; ++n) {
            int col = n0 + wco + n * 16 + fr;
            int part = col >> 10;
            int cn = col & 1023;
            int hh = cn >> 6, d = cn & 63, ii = d >> 1;
            bool evn = (d & 1) == 0;
#pragma unroll
            for (int m = 0; m < MM; ++m) {
                int row = m0 + wro + m * 16 + fq;
                int bh = (row >> 11) * 16 + hh;
                int tb = row & (Tv - 1);
                if (part == 2) {
                    int X = (d & 7) << 3;
                    int tile0 = tb & ~63, toff = tb & 63;
                    __bf16 ov[4];
#pragma unroll
                    for (int r = 0; r < 4; ++r) ov[r] = (__bf16)acc[m][n][r];
                    *(ull*)(vOut + ((long)bh * 64 + d) * Tv + tile0 + (toff ^ X)) = *(ull*)ov;
                } else {
                    float pxv[4];
#pragma unroll
                    for (int r = 0; r < 4; ++r) pxv[r] = __shfl_xor(acc[m][n][r], 1);
                    if (evn) {
#pragma unroll
                        for (int r = 0; r < 4; ++r) {
                            int t = tb + r;
                            float c = cosT[t * 32 + ii], s = sinT[t * 32 + ii];
                            float x0 = acc[m][n][r], x1 = pxv[r];
                            float r0 = x0 * c - x1 * s;
                            float r1 = x0 * s + x1 * c;
                            if (part == 0) {
                                __bf16 pr[2] = {(__bf16)(r0 * SCL), (__bf16)(r1 * SCL)};
                                *(unsigned int*)(qOut + (long)(row + r) * 1024 + cn) = *(unsigned int*)pr;
                            } else {
                                __bf16 pr[2] = {(__bf16)r0, (__bf16)r1};
                                char* base = (char*)(kOut + ((long)bh * Tv + t) * 64);
                                *(unsigned int*)(base + ((4 * ii) ^ ((t & 7) << 4))) = *(unsigned int*)pr;
                            }
                        }
                    }
                }
            }
        }
    }
}

// ---------------- fused FFN1+FFN2: 128x64 dual-acc, 1408 blocks (occupancy-first) ----------------
__global__ __launch_bounds__(256, 4) void k_ffn(const __bf16* __restrict__ A,
                                                const __bf16* __restrict__ B1,
                                                const __bf16* __restrict__ B2,
                                                const float* __restrict__ b1,
                                                const float* __restrict__ b2,
                                                __bf16* __restrict__ outH) {
    __shared__ __align__(16) __bf16 As[128][64];
    __shared__ __align__(16) __bf16 B1s[64][64];
    __shared__ __align__(16) __bf16 B2s[64][64];
    int tid = threadIdx.x, lane = tid & 63, wave = tid >> 6;
    int nwg = 32 * (HIDP >> 6);
    int flat = blockIdx.x;
    int orig = (flat & 7) * (nwg >> 3) + (flat >> 3);
    int m0 = (orig & 31) * 128;
    int n0 = (orig >> 5) * 64;
    int wro = (wave >> 1) * 64, wco = (wave & 1) * 32;
    int fr = lane & 15, fo2 = (lane >> 4) * 16;
    int sr = tid >> 3, sc = (tid & 7) * 8;
    f32x4 acc1[4][2] = {}, acc2[4][2] = {};
    for (int k0 = 0; k0 < Cv; k0 += 64) {
        __syncthreads();
#pragma unroll
        for (int i = 0; i < 4; ++i) {
            int r = i * 32 + sr;
            gload_lds16(A + (long)(m0 + r) * Cv + k0 + (sc ^ ((r & 7) << 3)), &As[r][sc]);
        }
#pragma unroll
        for (int i = 0; i < 2; ++i) {
            int r = i * 32 + sr;
            int scs = sc ^ ((r & 7) << 3);
            gload_lds16(B1 + (long)(n0 + r) * Cv + k0 + scs, &B1s[r][sc]);
            gload_lds16(B2 + (long)(n0 + r) * Cv + k0 + scs, &B2s[r][sc]);
        }
        __syncthreads();
#pragma unroll
        for (int s = 0; s < 2; ++s) {
            bf16x8 af[4], b1f[2], b2f[2];
#pragma unroll
            for (int m = 0; m < 4; ++m) {
                int r = wro + m * 16 + fr;
                af[m] = *(const bf16x8*)((const char*)&As[r][0] + ((s * 64 + fo2) ^ ((r & 7) << 4)));
            }
#pragma unroll
            for (int n = 0; n < 2; ++n) {
                int r = wco + n * 16 + fr;
                b1f[n] = *(const bf16x8*)((const char*)&B1s[r][0] + ((s * 64 + fo2) ^ ((r & 7) << 4)));
                b2f[n] = *(const bf16x8*)((const char*)&B2s[r][0] + ((s * 64 + fo2) ^ ((r & 7) << 4)));
            }
            __builtin_amdgcn_s_setprio(1);
#pragma unroll
            for (int m = 0; m < 4; ++m)
#pragma unroll
                for (int n = 0; n < 2; ++n) {
                    acc1[m][n] = __builtin_amdgcn_mfma_f32_16x16x32_bf16(af[m], b1f[n], acc1[m][n], 0, 0, 0);
                    acc2[m][n] = __builtin_amdgcn_mfma_f32_16x16x32_bf16(af[m], b2f[n], acc2[m][n], 0, 0, 0);
                }
            __builtin_amdgcn_s_setprio(0);
        }
    }
    int fq = (lane >> 4) * 4;
#pragma unroll
    for (int m = 0; m < 4; ++m)
#pragma unroll
        for (int n = 0; n < 2; ++n) {
            int row = m0 + wro + m * 16 + fq;
            int col = n0 + wco + n * 16 + fr;
            float b1v = (col < HIDv) ? b1[col] : 0.0f;
            float b2v = (col < HIDv) ? b2[col] : 0.0f;
#pragma unroll
            for (int r = 0; r < 4; ++r) {
                float c1 = acc1[m][n][r] + b1v;
                float c2 = acc2[m][n][r] + b2v;
                float sw = c1 * (1.0f + __expf(-c1));
                outH[(long)(row + r) * HIDP + col] = (__bf16)(sw * c2);
            }
        }
}

// ---------------- flash attention (QBLK=64, KBLK=128, single-buffer, 4 blk/CU) ----------------
__global__ __launch_bounds__(256) void k_attn(const __bf16* __restrict__ Q,
                                              const __bf16* __restrict__ KR,
                                              const __bf16* __restrict__ VT,
                                              __bf16* __restrict__ O) {
    __shared__ __align__(16) __bf16 Ks[128][64];
    __shared__ __align__(16) __bf16 Vs[64][128];
    __shared__ __align__(16) __bf16 Ps[4][16][64];
    int tid = threadIdx.x, lane = tid & 63, w = tid >> 6;
    int bh = blockIdx.x & 31;
    int qt = 31 - (blockIdx.x >> 5);
    int q0 = qt * 64;
    int hi = qt & 1;
    int b = bh >> 4, h = bh & 15;
    const long qbase = ((long)b * Tv) * Cv + h * HSv;
    const long kbase = (long)bh * Tv * 64;
    const long vbase = (long)bh * 64 * Tv;
    int fr = lane & 15, g = lane >> 4;
    int go = g * 8;
    int xr = (fr & 7) << 4;
    int qrow = q0 + w * 16 + fr;
    bf16x8 qf0 = *(const bf16x8*)(Q + qbase + (long)qrow * Cv + go);
    bf16x8 qf1 = *(const bf16x8*)(Q + qbase + (long)qrow * Cv + 32 + go);

    bf16x8 ones;
#pragma unroll
    for (int e = 0; e < 8; ++e) ones[e] = (__bf16)1.0f;

    f32x4 o[4] = {};
    f32x4 ls = {};
    float mrow = -INFINITY;

    auto stage = [&](int j0) {
#pragma unroll
        for (int i = 0; i < 4; ++i) {
            int rk = i * 32 + w * 8 + (lane >> 3);
            gload_lds16(KR + kbase + (long)(j0 + rk) * 64 + (lane & 7) * 8,
                        &Ks[rk][(lane & 7) * 8]);
        }
#pragma unroll
        for (int i = 0; i < 4; ++i) {
            int rv = w * 16 + i * 4 + (lane >> 4);
            gload_lds16(VT + vbase + (long)rv * Tv + j0 + (lane & 15) * 8,
                        &Vs[rv][(lane & 15) * 8]);
        }
    };

    int nt = (qt >> 1) + 1;
    stage(0);
    for (int t = 0; t < nt; ++t) {
        __syncthreads();
        bool diag = (t == nt - 1);
        int kkmax = diag ? (w + (hi ? 4 : 0)) : 7;
        f32x4 s4[8];
        __builtin_amdgcn_s_setprio(1);
#pragma unroll
        for (int kk = 0; kk < 8; ++kk) {
            if (kk <= kkmax) {
                int key = kk * 16 + fr;
                const char* krow = (const char*)&Ks[key][0];
                bf16x8 kf0 = *(const bf16x8*)(krow + ((go * 2) ^ ((key & 7) << 4)));
                bf16x8 kf1 = *(const bf16x8*)(krow + ((64 + go * 2) ^ ((key & 7) << 4)));
                f32x4 z = {};
                z = __builtin_amdgcn_mfma_f32_16x16x32_bf16(kf0, qf0, z, 0, 0, 0);
                z = __builtin_amdgcn_mfma_f32_16x16x32_bf16(kf1, qf1, z, 0, 0, 0);
                s4[kk] = z;
            } else {
                f32x4 ninf = {-INFINITY, -INFINITY, -INFINITY, -INFINITY};
                s4[kk] = ninf;
            }
        }
        __builtin_amdgcn_s_setprio(0);
        if (diag) {
            int qloc = hi * 64 + w * 16 + fr;
#pragma unroll
            for (int kk = 0; kk < 8; ++kk)
#pragma unroll
                for (int r = 0; r < 4; ++r) {
                    int key = kk * 16 + g * 4 + r;
                    if (key > qloc) s4[kk][r] = -INFINITY;
                }
        }
        float pmax = s4[0][0];
#pragma unroll
        for (int kk = 0; kk < 8; ++kk)
#pragma unroll
            for (int r = 0; r < 4; ++r) pmax = fmaxf(pmax, s4[kk][r]);
        pmax = fmaxf(pmax, __shfl_xor(pmax, 16));
        pmax = fmaxf(pmax, __shfl_xor(pmax, 32));
        if (!__all(pmax - mrow <= 8.0f)) {
            float mn = fmaxf(mrow, pmax);
            float alpha = exp2f(mrow - mn);
            mrow = mn;
#pragma unroll
            for (int r = 0; r < 4; ++r) ls[r] *= alpha;
#pragma unroll
            for (int fb = 0; fb < 4; ++fb)
#pragma unroll
                for (int r = 0; r < 4; ++r) o[fb][r] *= alpha;
        }
        char* prow = (char*)&Ps[w][fr][0];
#pragma unroll
        for (int hf = 0; hf < 2; ++hf) {
            if (diag && !hi && hf == 1) break;
#pragma unroll
            for (int kk = 0; kk < 4; ++kk) {
                int ks = hf * 4 + kk;
                __bf16 pk[4];
#pragma unroll
                for (int r = 0; r < 4; ++r) pk[r] = (__bf16)exp2f(s4[ks][r] - mrow);
                *(ull*)(prow + ((kk * 32 + g * 8) ^ xr)) = *(ull*)pk;
            }
            bf16x8 pa0 = *(const bf16x8*)(prow + ((g * 16) ^ xr));
            bf16x8 pa1 = *(const bf16x8*)(prow + ((64 + g * 16) ^ xr));
            __builtin_amdgcn_s_setprio(1);
            ls = __builtin_amdgcn_mfma_f32_16x16x32_bf16(ones, pa0, ls, 0, 0, 0);
            ls = __builtin_amdgcn_mfma_f32_16x16x32_bf16(ones, pa1, ls, 0, 0, 0);
#pragma unroll
            for (int fb = 0; fb < 4; ++fb) {
                int vrow = fb * 16 + fr;
                const char* vrd = (const char*)&Vs[vrow][0];
                bf16x8 v0 = *(const bf16x8*)(vrd + hf * 128 + ((go * 2) ^ ((vrow & 7) << 4)));
                bf16x8 v1 = *(const bf16x8*)(vrd + hf * 128 + ((64 + go * 2) ^ ((vrow & 7) << 4)));
                o[fb] = __builtin_amdgcn_mfma_f32_16x16x32_bf16(v0, pa0, o[fb], 0, 0, 0);
                o[fb] = __builtin_amdgcn_mfma_f32_16x16x32_bf16(v1, pa1, o[fb], 0, 0, 0);
            }
            __builtin_amdgcn_s_setprio(0);
        }
        if (t + 1 < nt) {
            __syncthreads();
            stage((t + 1) * 128);
        }
    }
    float rl = 1.0f / ls[0];
#pragma unroll
    for (int fb = 0; fb < 4; ++fb) {
        __bf16 ov[4];
#pragma unroll
        for (int r = 0; r < 4; ++r) ov[r] = (__bf16)(o[fb][r] * rl);
        *(ull*)(O + qbase + (long)qrow * Cv + fb * 16 + g * 4) = *(ull*)ov;
    }
}

// ---------------- launch ----------------
extern "C" void kernel_launch(void* const* d_in, const int* in_sizes, int n_in,
                              void* d_out, int out_size, void* d_ws, size_t ws_size,
                              hipStream_t stream) {
    const float* x    = (const float*)d_in[0];
    const float* ln1w = (const float*)d_in[1];
    const float* Wq   = (const float*)d_in[2];
    const float* Wk   = (const float*)d_in[3];
    const float* Wv   = (const float*)d_in[4];
    const float* Wo   = (const float*)d_in[5];
    const float* bo   = (const float*)d_in[6];
    const float* w1   = (const float*)d_in[7];
    const float* b1   = (const float*)d_in[8];
    const float* w2   = (const float*)d_in[9];
    const float* b2   = (const float*)d_in[10];
    const float* w3   = (const float*)d_in[11];
    const float* b3   = (const float*)d_in[12];
    const float* ln2w = (const float*)d_in[13];
    const float* cosT = (const float*)d_in[14];
    const float* sinT = (const float*)d_in[15];
    float* out = (float*)d_out;

    char* p = (char*)d_ws;
    auto alloc = [&](size_t bytes) {
        char* r = p;
        p += (bytes + 255) & ~(size_t)255;
        return r;
    };
    __bf16* qh  = (__bf16*)alloc((size_t)Mv * Cv * 2);
    __bf16* ah  = (__bf16*)alloc((size_t)Mv * Cv * 2);
    __bf16* x1h = (__bf16*)alloc((size_t)Mv * Cv * 2);
    __bf16* x2h = (__bf16*)alloc((size_t)Mv * Cv * 2);
    __bf16* x3h = (__bf16*)alloc((size_t)Mv * Cv * 2);
    __bf16* KR  = (__bf16*)alloc((size_t)Bv * Hv * Tv * HSv * 2);
    __bf16* VT  = (__bf16*)alloc((size_t)Bv * Hv * HSv * Tv * 2);
    __bf16* hh  = (__bf16*)alloc((size_t)Mv * HIDP * 2);
    __bf16* wqkvh = (__bf16*)alloc((size_t)3072 * Cv * 2);
    __bf16* woh = (__bf16*)alloc((size_t)Cv * Cv * 2);
    __bf16* w1h = (__bf16*)alloc((size_t)HIDP * Cv * 2);
    __bf16* w2h = (__bf16*)alloc((size_t)HIDP * Cv * 2);
    __bf16* w3h = (__bf16*)alloc((size_t)Cv * HIDP * 2);

    const long nCC = (long)Cv * Cv;
    CastArgs ca;
    ca.seg[0] = {Wq, wqkvh,           nCC, nCC, 0, 0};
    ca.seg[1] = {Wk, wqkvh + nCC,     nCC, nCC, 0, 0};
    ca.seg[2] = {Wv, wqkvh + 2 * nCC, nCC, nCC, 0, 0};
    ca.seg[3] = {Wo, woh,             nCC, nCC, 0, 0};
    ca.seg[4] = {w1, w1h, (long)HIDv * Cv, (long)HIDP * Cv, 0, 0};
    ca.seg[5] = {w2, w2h, (long)HIDv * Cv, (long)HIDP * Cv, 0, 0};
    ca.seg[6] = {w3, w3h, (long)Cv * HIDv, (long)Cv * HIDP, HIDv, HIDP};

    // weight cast + rmsnorm1 in one launch
    k_prep<<<2048 + Mv, 256, 0, stream>>>(ca, x, ln1w, x1h);

    // QKV GEMM with fused RoPE(+Q prescale) + V-transpose epilogue
    k_gemm<128, 128, 4><<<768, 256, 0, stream>>>(x1h, wqkvh, Mv, 3072, Cv,
        nullptr, nullptr, nullptr, nullptr, qh, KR, VT, cosT, sinT);

    k_attn<<<1024, 256, 0, stream>>>(qh, KR, VT, ah);

    // x2 = bf16(x1 + attn @ Wo^T + bo)  — 64x64 tile, 1024 blocks
    k_gemm<64, 64, 2><<<1024, 256, 0, stream>>>(ah, woh, Mv, Cv, Cv,
        nullptr, x2h, bo, x1h, nullptr, nullptr, nullptr, nullptr, nullptr);

    k_rmsnorm_h<<<Mv, 256, 0, stream>>>(x2h, ln2w, x3h);

    // hh = swish_bug(x3@w1^T + b1) * (x3@w2^T + b2)  — 128x64 dual, 1408 blocks
    k_ffn<<<1408, 256, 0, stream>>>(x3h, w1h, w2h, b1, b2, hh);

    // out = x3 + hh @ w3^T + b3  — 64x64 tile, 1024 blocks
    k_gemm<64, 64, 1><<<1024, 256, 0, stream>>>(hh, w3h, Mv, Cv, HIDP,
        out, nullptr, b3, x3h, nullptr, nullptr, nullptr, nullptr, nullptr);
}